// Round 1
// baseline (521.252 us; speedup 1.0000x reference)
//
#include <hip/hip_runtime.h>
#include <cstdint>
#include <cstddef>

// ---------------- degree count ----------------
__global__ __launch_bounds__(256) void k_count(const int* __restrict__ col,
                                               int* __restrict__ cnt, int E) {
  int e = blockIdx.x * 256 + threadIdx.x;
  if (e < E) atomicAdd(&cnt[col[e]], 1);
}

// ---------------- exclusive scan (1 block) + dinv ----------------
__global__ __launch_bounds__(1024) void k_scan(const int* __restrict__ cnt,
                                               int* __restrict__ off,
                                               int* __restrict__ cursor,
                                               float* __restrict__ dinv, int N) {
  __shared__ int wsum[16];
  __shared__ int carry;
  int tid = threadIdx.x, lane = tid & 63, wv = tid >> 6;
  if (tid == 0) carry = 0;
  __syncthreads();
  for (int base = 0; base < N; base += 1024) {
    int i = base + tid;
    int v = (i < N) ? cnt[i] : 0;
    int inc = v;
#pragma unroll
    for (int o = 1; o < 64; o <<= 1) {
      int t = __shfl_up(inc, o);
      if (lane >= o) inc += t;
    }
    if (lane == 63) wsum[wv] = inc;
    __syncthreads();
    if (tid == 0) {
      int s = carry;
      for (int w2 = 0; w2 < 16; ++w2) { int t = wsum[w2]; wsum[w2] = s; s += t; }
      carry = s;
    }
    __syncthreads();
    if (i < N) {
      int excl = wsum[wv] + inc - v;
      off[i] = excl;
      cursor[i] = excl;
      dinv[i] = rsqrtf((float)v + 1.0f);
    }
    __syncthreads();
  }
  if (tid == 0) off[N] = carry;
}

// ---------------- scatter edges into CSR (sorted by target) ----------------
__global__ __launch_bounds__(256) void k_scatter(const int* __restrict__ ei,
                                                 const float* __restrict__ dinv,
                                                 int* __restrict__ cursor,
                                                 int* __restrict__ srcs,
                                                 float* __restrict__ wsrt, int E) {
  int e = blockIdx.x * 256 + threadIdx.x;
  if (e >= E) return;
  int s = ei[e], d = ei[E + e];
  float w = dinv[s] * dinv[d];
  int p = atomicAdd(&cursor[d], 1);
  srcs[p] = s;
  wsrt[p] = w;
}

// ---------------- fused 3x GEMM: h = x @ W^T + b (relu for W_i) ----------------
__global__ __launch_bounds__(256) void k_gemm(const float* __restrict__ x,
    const float* __restrict__ W_hp, const float* __restrict__ b_hp,
    const float* __restrict__ W_lp, const float* __restrict__ b_lp,
    const float* __restrict__ W_i,  const float* __restrict__ b_i,
    float* __restrict__ h_hp, float* __restrict__ h_lp, float* __restrict__ Hi,
    int N) {
  const float* W; const float* b; float* out; bool dorelu = false;
  if (blockIdx.y == 0)      { W = W_hp; b = b_hp; out = h_hp; }
  else if (blockIdx.y == 1) { W = W_lp; b = b_lp; out = h_lp; }
  else                      { W = W_i;  b = b_i;  out = Hi; dorelu = true; }

  __shared__ float Ws[128 * 129];  // pad row stride to 129 -> 2-way (free) bank aliasing
  for (int idx = threadIdx.x * 4; idx < 16384; idx += 1024) {
    float4 v = *(const float4*)(W + idx);
    int c = idx >> 7, k = idx & 127;
    float* p = &Ws[c * 129 + k];
    p[0] = v.x; p[1] = v.y; p[2] = v.z; p[3] = v.w;
  }
  __syncthreads();

  int wv = (int)threadIdx.x >> 6, lane = (int)threadIdx.x & 63;
  int r0 = (blockIdx.x * 4 + wv) * 16;
  if (r0 >= N) return;
  int c0 = lane * 2;

  // per-row base pointers (clamped for tail safety)
  const float* rp[16];
#pragma unroll
  for (int r = 0; r < 16; ++r) {
    int rr = r0 + r; if (rr > N - 1) rr = N - 1;
    rp[r] = x + (size_t)rr * 128;
  }

  float acc0[16], acc1[16];
  float bb0 = b[c0], bb1 = b[c0 + 1];
#pragma unroll
  for (int r = 0; r < 16; ++r) { acc0[r] = bb0; acc1[r] = bb1; }

  for (int k0 = 0; k0 < 128; k0 += 4) {
    float w0[4], w1[4];
#pragma unroll
    for (int j = 0; j < 4; ++j) {
      w0[j] = Ws[c0 * 129 + k0 + j];
      w1[j] = Ws[(c0 + 1) * 129 + k0 + j];
    }
#pragma unroll
    for (int r = 0; r < 16; ++r) {
      float4 xv = *(const float4*)(rp[r] + k0);
      acc0[r] += xv.x * w0[0] + xv.y * w0[1] + xv.z * w0[2] + xv.w * w0[3];
      acc1[r] += xv.x * w1[0] + xv.y * w1[1] + xv.z * w1[2] + xv.w * w1[3];
    }
  }

#pragma unroll
  for (int r = 0; r < 16; ++r) {
    int rr = r0 + r;
    if (rr >= N) break;
    float v0 = acc0[r], v1 = acc1[r];
    if (dorelu) { v0 = fmaxf(v0, 0.f); v1 = fmaxf(v1, 0.f); }
    float2 st; st.x = v0; st.y = v1;
    *(float2*)(out + (size_t)rr * 128 + c0) = st;
  }
}

// ---------------- fused aggregation + epilogue (one wave per node) ----------------
__global__ __launch_bounds__(256) void k_agg_final(
    const float* __restrict__ h_hp, const float* __restrict__ h_lp,
    const float* __restrict__ Hi, const float* __restrict__ dinv,
    const int* __restrict__ off, const int* __restrict__ srcs,
    const float* __restrict__ wsrt,
    const float* __restrict__ wlh, const float* __restrict__ wll,
    const float* __restrict__ wli,
    const float* __restrict__ pbh, const float* __restrict__ pbl,
    const float* __restrict__ pbi,
    float* __restrict__ out, int N) {
  int wv = __builtin_amdgcn_readfirstlane((int)threadIdx.x >> 6);
  int lane = (int)threadIdx.x & 63;
  int node = blockIdx.x * 4 + wv;
  if (node >= N) return;

  int p0 = off[node], p1 = off[node + 1];
  float ah0 = 0.f, ah1 = 0.f, al0 = 0.f, al1 = 0.f;
  for (int p = p0; p < p1; ++p) {
    int s = srcs[p];
    float w = wsrt[p];
    const float* hp = h_hp + (size_t)s * 128;
    const float* lp = h_lp + (size_t)s * 128;
    ah0 = fmaf(w, hp[lane], ah0);
    ah1 = fmaf(w, hp[64 + lane], ah1);
    al0 = fmaf(w, lp[lane], al0);
    al1 = fmaf(w, lp[64 + lane], al1);
  }
  float di = dinv[node], wself = di * di;
  const float* hs = h_hp + (size_t)node * 128;
  const float* ls = h_lp + (size_t)node * 128;
  float hs0 = hs[lane], hs1 = hs[64 + lane];
  float ls0 = ls[lane], ls1 = ls[64 + lane];
  ah0 += wself * hs0; ah1 += wself * hs1;
  al0 += wself * ls0; al1 += wself * ls1;

  float Hh0 = fmaxf(hs0 - ah0, 0.f), Hh1 = fmaxf(hs1 - ah1, 0.f);
  float Hl0 = fmaxf(al0, 0.f),       Hl1 = fmaxf(al1, 0.f);
  const float* is = Hi + (size_t)node * 128;
  float Hi0 = is[lane], Hi1 = is[64 + lane];

  float dh = Hh0 * wlh[lane] + Hh1 * wlh[64 + lane];
  float dl = Hl0 * wll[lane] + Hl1 * wll[64 + lane];
  float dd = Hi0 * wli[lane] + Hi1 * wli[64 + lane];
#pragma unroll
  for (int o = 32; o > 0; o >>= 1) {
    dh += __shfl_xor(dh, o);
    dl += __shfl_xor(dl, o);
    dd += __shfl_xor(dd, o);
  }
  float a_h = 1.f / (1.f + __expf(-(dh + pbh[0])));
  float a_l = 1.f / (1.f + __expf(-(dl + pbl[0])));
  float a_i = 1.f / (1.f + __expf(-(dd + pbi[0])));

  out[(size_t)node * 128 + lane]      = a_h * Hh0 + a_l * Hl0 + a_i * Hi0;
  out[(size_t)node * 128 + 64 + lane] = a_h * Hh1 + a_l * Hl1 + a_i * Hi1;
}

// ---------------- launch ----------------
extern "C" void kernel_launch(void* const* d_in, const int* in_sizes, int n_in,
                              void* d_out, int out_size, void* d_ws, size_t ws_size,
                              hipStream_t stream) {
  const float* x     = (const float*)d_in[0];
  const int*   ei    = (const int*)d_in[1];
  const float* W_hp  = (const float*)d_in[2];
  const float* b_hp  = (const float*)d_in[3];
  const float* W_lp  = (const float*)d_in[4];
  const float* b_lp  = (const float*)d_in[5];
  const float* W_i   = (const float*)d_in[6];
  const float* b_i   = (const float*)d_in[7];
  const float* wlh   = (const float*)d_in[8];
  const float* pbh   = (const float*)d_in[9];
  const float* wll   = (const float*)d_in[10];
  const float* pbl   = (const float*)d_in[11];
  const float* wli   = (const float*)d_in[12];
  const float* pbi   = (const float*)d_in[13];
  float* out = (float*)d_out;

  int N = in_sizes[0] / 128;
  int E = in_sizes[1] / 2;
  size_t N128 = (size_t)N * 128;

  float* h_hp  = (float*)d_ws;
  float* h_lp  = h_hp + N128;
  float* Hi    = h_lp + N128;
  float* dinv  = Hi + N128;
  int*   cnt   = (int*)(dinv + N);
  int*   off   = cnt + N;
  int*   cursor= off + N + 1;
  int*   srcs  = cursor + N;
  float* wsrt  = (float*)(srcs + E);

  hipMemsetAsync(cnt, 0, sizeof(int) * N, stream);
  k_count<<<(E + 255) / 256, 256, 0, stream>>>(ei + E, cnt, E);
  k_scan<<<1, 1024, 0, stream>>>(cnt, off, cursor, dinv, N);
  k_scatter<<<(E + 255) / 256, 256, 0, stream>>>(ei, dinv, cursor, srcs, wsrt, E);
  k_gemm<<<dim3((N + 63) / 64, 3), 256, 0, stream>>>(
      x, W_hp, b_hp, W_lp, b_lp, W_i, b_i, h_hp, h_lp, Hi, N);
  k_agg_final<<<(N + 3) / 4, 256, 0, stream>>>(
      h_hp, h_lp, Hi, dinv, off, srcs, wsrt, wlh, wll, wli, pbh, pbl, pbi, out, N);
}

// Round 2
// 476.539 us; speedup vs baseline: 1.0938x; 1.0938x over previous
//
#include <hip/hip_runtime.h>
#include <cstdint>
#include <cstddef>

#define DEV __device__ __forceinline__

DEV float4 shfl_xor4(float4 v, int m) {
  float4 r;
  r.x = __shfl_xor(v.x, m); r.y = __shfl_xor(v.y, m);
  r.z = __shfl_xor(v.z, m); r.w = __shfl_xor(v.w, m);
  return r;
}

// ---------------- degree count ----------------
__global__ __launch_bounds__(256) void k_count(const int* __restrict__ col,
                                               int* __restrict__ cnt, int E) {
  int e = blockIdx.x * 256 + threadIdx.x;
  if (e < E) atomicAdd(&cnt[e < E ? col[e] : 0], 1);
}

// ---------------- phase A: per-block scan (256 elems) ----------------
__global__ __launch_bounds__(256) void k_blockscan(const int* __restrict__ cnt,
                                                   int* __restrict__ off,
                                                   float* __restrict__ dinv,
                                                   int* __restrict__ btot, int N) {
  __shared__ int ws[4];
  int t = threadIdx.x, lane = t & 63, wv = t >> 6;
  int i = blockIdx.x * 256 + t;
  int v = (i < N) ? cnt[i] : 0;
  int inc = v;
#pragma unroll
  for (int o = 1; o < 64; o <<= 1) {
    int u = __shfl_up(inc, o);
    if (lane >= o) inc += u;
  }
  if (lane == 63) ws[wv] = inc;
  __syncthreads();
  if (t == 0) {
    int s = 0;
#pragma unroll
    for (int w = 0; w < 4; ++w) { int tmp = ws[w]; ws[w] = s; s += tmp; }
  }
  __syncthreads();
  int excl = ws[wv] + inc - v;
  if (i < N) {
    off[i] = excl;
    dinv[i] = rsqrtf((float)v + 1.0f);
  }
  if (t == 255) btot[blockIdx.x] = excl + v;
}

// ---------------- phase B: scan of block totals (NB <= 256) ----------------
__global__ __launch_bounds__(256) void k_scanb(const int* __restrict__ btot,
                                               int* __restrict__ bpre,
                                               int* __restrict__ off, int N, int NB) {
  __shared__ int ws[4];
  int t = threadIdx.x, lane = t & 63, wv = t >> 6;
  int v = (t < NB) ? btot[t] : 0;
  int inc = v;
#pragma unroll
  for (int o = 1; o < 64; o <<= 1) {
    int u = __shfl_up(inc, o);
    if (lane >= o) inc += u;
  }
  if (lane == 63) ws[wv] = inc;
  __syncthreads();
  if (t == 0) {
    int s = 0;
#pragma unroll
    for (int w = 0; w < 4; ++w) { int tmp = ws[w]; ws[w] = s; s += tmp; }
  }
  __syncthreads();
  int excl = ws[wv] + inc - v;
  if (t < NB) bpre[t] = excl;
  if (t == 255) off[N] = excl + v;  // grand total = E
}

// ---------------- phase C: add block prefix ----------------
__global__ __launch_bounds__(256) void k_addoff(int* __restrict__ off,
                                                const int* __restrict__ bpre,
                                                int* __restrict__ cursor, int N) {
  int i = blockIdx.x * 256 + threadIdx.x;
  if (i < N) {
    int o = off[i] + bpre[blockIdx.x];
    off[i] = o;
    cursor[i] = o;
  }
}

// ---------------- scatter edges into CSR (sorted by target) ----------------
__global__ __launch_bounds__(256) void k_scatter(const int* __restrict__ ei,
                                                 const float* __restrict__ dinv,
                                                 int* __restrict__ cursor,
                                                 int* __restrict__ srcs,
                                                 float* __restrict__ wsrt, int E) {
  int e = blockIdx.x * 256 + threadIdx.x;
  if (e >= E) return;
  int s = ei[e], d = ei[E + e];
  float w = dinv[s] * dinv[d];
  int p = atomicAdd(&cursor[d], 1);
  srcs[p] = s;
  wsrt[p] = w;
}

// ---------------- fused 3x GEMM: h = x @ W^T + b ----------------
// blockIdx.y: 0 -> h_hp into h_cat[:,0:128]; 1 -> h_lp into h_cat[:,128:256];
//             2 -> relu(x@W_i^T+b) into Hi (stride 128)
// 512 threads (8 waves x 16 rows = 128-row tile). W transposed in LDS:
// Wt[k*128+c]; lane reads float2 at byte k*512+8*lane -> linear -> conflict-free.
__global__ __launch_bounds__(512) void k_gemm(const float* __restrict__ x,
    const float* __restrict__ W_hp, const float* __restrict__ b_hp,
    const float* __restrict__ W_lp, const float* __restrict__ b_lp,
    const float* __restrict__ W_i,  const float* __restrict__ b_i,
    float* __restrict__ h_cat, float* __restrict__ Hi, int N) {
  const float* W; const float* b; float* out; int ostride; bool dorelu = false;
  if (blockIdx.y == 0)      { W = W_hp; b = b_hp; out = h_cat;       ostride = 256; }
  else if (blockIdx.y == 1) { W = W_lp; b = b_lp; out = h_cat + 128; ostride = 256; }
  else                      { W = W_i;  b = b_i;  out = Hi;          ostride = 128; dorelu = true; }

  __shared__ float Wt[128 * 128];  // 64 KB: Wt[k][c]
  for (int idx = threadIdx.x * 4; idx < 16384; idx += 2048) {
    float4 v = *(const float4*)(W + idx);
    int c = idx >> 7, k = idx & 127;
    Wt[(k + 0) * 128 + c] = v.x;
    Wt[(k + 1) * 128 + c] = v.y;
    Wt[(k + 2) * 128 + c] = v.z;
    Wt[(k + 3) * 128 + c] = v.w;
  }
  __syncthreads();

  int wv = (int)threadIdx.x >> 6, lane = (int)threadIdx.x & 63;
  int c0 = lane * 2;
  float bb0 = b[c0], bb1 = b[c0 + 1];

  int r0 = blockIdx.x * 128 + wv * 16;
  if (r0 >= N) return;
  int nr = N - r0; if (nr > 16) nr = 16;

  float acc0[16], acc1[16];
#pragma unroll
  for (int r = 0; r < 16; ++r) { acc0[r] = bb0; acc1[r] = bb1; }

  const float* bp = x + (size_t)r0 * 128;

  if (nr == 16) {
    for (int k0 = 0; k0 < 128; k0 += 4) {
      float2 w0 = *(const float2*)&Wt[(k0 + 0) * 128 + c0];
      float2 w1 = *(const float2*)&Wt[(k0 + 1) * 128 + c0];
      float2 w2 = *(const float2*)&Wt[(k0 + 2) * 128 + c0];
      float2 w3 = *(const float2*)&Wt[(k0 + 3) * 128 + c0];
#pragma unroll
      for (int rb = 0; rb < 16; rb += 4) {
        float4 xv[4];
#pragma unroll
        for (int j = 0; j < 4; ++j)
          xv[j] = *(const float4*)(bp + (rb + j) * 128 + k0);
#pragma unroll
        for (int j = 0; j < 4; ++j) {
          int r = rb + j;
          acc0[r] = fmaf(xv[j].x, w0.x, acc0[r]);
          acc0[r] = fmaf(xv[j].y, w1.x, acc0[r]);
          acc0[r] = fmaf(xv[j].z, w2.x, acc0[r]);
          acc0[r] = fmaf(xv[j].w, w3.x, acc0[r]);
          acc1[r] = fmaf(xv[j].x, w0.y, acc1[r]);
          acc1[r] = fmaf(xv[j].y, w1.y, acc1[r]);
          acc1[r] = fmaf(xv[j].z, w2.y, acc1[r]);
          acc1[r] = fmaf(xv[j].w, w3.y, acc1[r]);
        }
      }
    }
  } else {
    for (int k0 = 0; k0 < 128; k0 += 4) {
      float2 w0 = *(const float2*)&Wt[(k0 + 0) * 128 + c0];
      float2 w1 = *(const float2*)&Wt[(k0 + 1) * 128 + c0];
      float2 w2 = *(const float2*)&Wt[(k0 + 2) * 128 + c0];
      float2 w3 = *(const float2*)&Wt[(k0 + 3) * 128 + c0];
      for (int r = 0; r < nr; ++r) {
        float4 xv = *(const float4*)(bp + r * 128 + k0);
        acc0[r] = fmaf(xv.x, w0.x, acc0[r]);
        acc0[r] = fmaf(xv.y, w1.x, acc0[r]);
        acc0[r] = fmaf(xv.z, w2.x, acc0[r]);
        acc0[r] = fmaf(xv.w, w3.x, acc0[r]);
        acc1[r] = fmaf(xv.x, w0.y, acc1[r]);
        acc1[r] = fmaf(xv.y, w1.y, acc1[r]);
        acc1[r] = fmaf(xv.z, w2.y, acc1[r]);
        acc1[r] = fmaf(xv.w, w3.y, acc1[r]);
      }
    }
  }

#pragma unroll
  for (int r = 0; r < 16; ++r) {
    if (r >= nr) break;
    float v0 = acc0[r], v1 = acc1[r];
    if (dorelu) { v0 = fmaxf(v0, 0.f); v1 = fmaxf(v1, 0.f); }
    float2 st; st.x = v0; st.y = v1;
    *(float2*)(out + (size_t)(r0 + r) * ostride + c0) = st;
  }
}

// ---------------- fused aggregation + epilogue (one wave per node) ----------------
// h_cat row: [0:128]=h_hp, [128:256]=h_lp. Lane l covers elems 4l..4l+3 of the
// 256-vector -> ONE coalesced dwordx4 gather per edge covers both matrices.
__global__ __launch_bounds__(256) void k_agg_final(
    const float* __restrict__ h_cat, const float* __restrict__ Hi,
    const float* __restrict__ dinv,
    const int* __restrict__ off, const int* __restrict__ srcs,
    const float* __restrict__ wsrt,
    const float* __restrict__ wlh, const float* __restrict__ wll,
    const float* __restrict__ wli,
    const float* __restrict__ pbh, const float* __restrict__ pbl,
    const float* __restrict__ pbi,
    float* __restrict__ out, int N) {
  int wv = __builtin_amdgcn_readfirstlane((int)threadIdx.x >> 6);
  int lane = (int)threadIdx.x & 63;
  int node = blockIdx.x * 4 + wv;
  if (node >= N) return;

  const float* hb = h_cat + 4 * lane;  // + s*256 per edge
  int p0 = off[node], p1 = off[node + 1];

  float4 acca = {0.f, 0.f, 0.f, 0.f}, accb = {0.f, 0.f, 0.f, 0.f};
  int p = p0;
  for (; p + 2 <= p1; p += 2) {
    int s0 = srcs[p], s1 = srcs[p + 1];
    float w0 = wsrt[p], w1 = wsrt[p + 1];
    float4 v0 = *(const float4*)(hb + (size_t)s0 * 256);
    float4 v1 = *(const float4*)(hb + (size_t)s1 * 256);
    acca.x = fmaf(w0, v0.x, acca.x); acca.y = fmaf(w0, v0.y, acca.y);
    acca.z = fmaf(w0, v0.z, acca.z); acca.w = fmaf(w0, v0.w, acca.w);
    accb.x = fmaf(w1, v1.x, accb.x); accb.y = fmaf(w1, v1.y, accb.y);
    accb.z = fmaf(w1, v1.z, accb.z); accb.w = fmaf(w1, v1.w, accb.w);
  }
  if (p < p1) {
    int s0 = srcs[p]; float w0 = wsrt[p];
    float4 v0 = *(const float4*)(hb + (size_t)s0 * 256);
    acca.x = fmaf(w0, v0.x, acca.x); acca.y = fmaf(w0, v0.y, acca.y);
    acca.z = fmaf(w0, v0.z, acca.z); acca.w = fmaf(w0, v0.w, acca.w);
  }
  float4 own;
  own.x = acca.x + accb.x; own.y = acca.y + accb.y;
  own.z = acca.z + accb.z; own.w = acca.w + accb.w;

  float di = dinv[node], wself = di * di;
  float4 sv = *(const float4*)(h_cat + (size_t)node * 256 + 4 * lane);
  own.x = fmaf(wself, sv.x, own.x); own.y = fmaf(wself, sv.y, own.y);
  own.z = fmaf(wself, sv.z, own.z); own.w = fmaf(wself, sv.w, own.w);

  // exchange halves: lanes<32 hold hp-side, lanes>=32 hold lp-side (same cols)
  float4 oth = shfl_xor4(own, 32);
  float4 svo = shfl_xor4(sv, 32);
  bool hpside = (lane < 32);
  float4 hpSelf, aggHp, aggLp;
  hpSelf.x = hpside ? sv.x : svo.x; hpSelf.y = hpside ? sv.y : svo.y;
  hpSelf.z = hpside ? sv.z : svo.z; hpSelf.w = hpside ? sv.w : svo.w;
  aggHp.x = hpside ? own.x : oth.x; aggHp.y = hpside ? own.y : oth.y;
  aggHp.z = hpside ? own.z : oth.z; aggHp.w = hpside ? own.w : oth.w;
  aggLp.x = hpside ? oth.x : own.x; aggLp.y = hpside ? oth.y : own.y;
  aggLp.z = hpside ? oth.z : own.z; aggLp.w = hpside ? oth.w : own.w;

  float4 Hh, Hl;
  Hh.x = fmaxf(hpSelf.x - aggHp.x, 0.f); Hh.y = fmaxf(hpSelf.y - aggHp.y, 0.f);
  Hh.z = fmaxf(hpSelf.z - aggHp.z, 0.f); Hh.w = fmaxf(hpSelf.w - aggHp.w, 0.f);
  Hl.x = fmaxf(aggLp.x, 0.f); Hl.y = fmaxf(aggLp.y, 0.f);
  Hl.z = fmaxf(aggLp.z, 0.f); Hl.w = fmaxf(aggLp.w, 0.f);

  int c4 = 4 * (lane & 31);
  float4 hi4 = *(const float4*)(Hi + (size_t)node * 128 + c4);
  float4 wh = *(const float4*)(wlh + c4);
  float4 wl = *(const float4*)(wll + c4);
  float4 wi = *(const float4*)(wli + c4);

  float dh = Hh.x * wh.x + Hh.y * wh.y + Hh.z * wh.z + Hh.w * wh.w;
  float dl = Hl.x * wl.x + Hl.y * wl.y + Hl.z * wl.z + Hl.w * wl.w;
  float dd = hi4.x * wi.x + hi4.y * wi.y + hi4.z * wi.z + hi4.w * wi.w;
#pragma unroll
  for (int o = 32; o > 0; o >>= 1) {
    dh += __shfl_xor(dh, o);
    dl += __shfl_xor(dl, o);
    dd += __shfl_xor(dd, o);
  }
  // each column counted twice (both half-waves) -> x0.5
  float a_h = 1.f / (1.f + __expf(-(0.5f * dh + pbh[0])));
  float a_l = 1.f / (1.f + __expf(-(0.5f * dl + pbl[0])));
  float a_i = 1.f / (1.f + __expf(-(0.5f * dd + pbi[0])));

  if (hpside) {
    float4 o4;
    o4.x = a_h * Hh.x + a_l * Hl.x + a_i * hi4.x;
    o4.y = a_h * Hh.y + a_l * Hl.y + a_i * hi4.y;
    o4.z = a_h * Hh.z + a_l * Hl.z + a_i * hi4.z;
    o4.w = a_h * Hh.w + a_l * Hl.w + a_i * hi4.w;
    *(float4*)(out + (size_t)node * 128 + c4) = o4;
  }
}

// ---------------- launch ----------------
extern "C" void kernel_launch(void* const* d_in, const int* in_sizes, int n_in,
                              void* d_out, int out_size, void* d_ws, size_t ws_size,
                              hipStream_t stream) {
  const float* x     = (const float*)d_in[0];
  const int*   ei    = (const int*)d_in[1];
  const float* W_hp  = (const float*)d_in[2];
  const float* b_hp  = (const float*)d_in[3];
  const float* W_lp  = (const float*)d_in[4];
  const float* b_lp  = (const float*)d_in[5];
  const float* W_i   = (const float*)d_in[6];
  const float* b_i   = (const float*)d_in[7];
  const float* wlh   = (const float*)d_in[8];
  const float* pbh   = (const float*)d_in[9];
  const float* wll   = (const float*)d_in[10];
  const float* pbl   = (const float*)d_in[11];
  const float* wli   = (const float*)d_in[12];
  const float* pbi   = (const float*)d_in[13];
  float* out = (float*)d_out;

  int N = in_sizes[0] / 128;
  int E = in_sizes[1] / 2;
  int NB = (N + 255) / 256;

  float* h_cat = (float*)d_ws;                 // N*256
  float* Hi    = h_cat + (size_t)N * 256;      // N*128
  float* dinv  = Hi + (size_t)N * 128;         // N
  int*   cnt   = (int*)(dinv + N);             // N
  int*   off   = cnt + N;                      // N+1
  int*   cursor= off + N + 1;                  // N
  int*   srcs  = cursor + N;                   // E
  float* wsrt  = (float*)(srcs + E);           // E
  // btot/bpre overlap srcs region (srcs written later, in k_scatter)
  int*   btot  = srcs;
  int*   bpre  = srcs + 4096;

  hipMemsetAsync(cnt, 0, sizeof(int) * N, stream);
  k_count<<<(E + 255) / 256, 256, 0, stream>>>(ei + E, cnt, E);
  k_blockscan<<<NB, 256, 0, stream>>>(cnt, off, dinv, btot, N);
  k_scanb<<<1, 256, 0, stream>>>(btot, bpre, off, N, NB);
  k_addoff<<<NB, 256, 0, stream>>>(off, bpre, cursor, N);
  k_scatter<<<(E + 255) / 256, 256, 0, stream>>>(ei, dinv, cursor, srcs, wsrt, E);
  k_gemm<<<dim3((N + 127) / 128, 3), 512, 0, stream>>>(
      x, W_hp, b_hp, W_lp, b_lp, W_i, b_i, h_cat, Hi, N);
  k_agg_final<<<(N + 3) / 4, 256, 0, stream>>>(
      h_cat, Hi, dinv, off, srcs, wsrt, wlh, wll, wli, pbh, pbl, pbi, out, N);
}

// Round 3
// 278.098 us; speedup vs baseline: 1.8743x; 1.7136x over previous
//
#include <hip/hip_runtime.h>
#include <cstdint>
#include <cstddef>

#define DEV __device__ __forceinline__

typedef __bf16 bf16x8 __attribute__((ext_vector_type(8)));
typedef float f32x4 __attribute__((ext_vector_type(4)));

DEV ushort f2b(float f) {
  uint u = __float_as_uint(f);
  return (ushort)((u + 0x7FFFu + ((u >> 16) & 1u)) >> 16);
}

DEV float4 shfl_xor4(float4 v, int m) {
  float4 r;
  r.x = __shfl_xor(v.x, m); r.y = __shfl_xor(v.y, m);
  r.z = __shfl_xor(v.z, m); r.w = __shfl_xor(v.w, m);
  return r;
}

DEV float4 unpack4(uint2 u) {
  float4 r;
  r.x = __uint_as_float(u.x << 16);
  r.y = __uint_as_float(u.x & 0xFFFF0000u);
  r.z = __uint_as_float(u.y << 16);
  r.w = __uint_as_float(u.y & 0xFFFF0000u);
  return r;
}

DEV void fma4(float4& a, float w, uint2 u) {
  float4 v = unpack4(u);
  a.x = fmaf(w, v.x, a.x); a.y = fmaf(w, v.y, a.y);
  a.z = fmaf(w, v.z, a.z); a.w = fmaf(w, v.w, a.w);
}

// ---------------- fp32 -> bf16 converts ----------------
__global__ __launch_bounds__(256) void k_cvt_x(const float* __restrict__ x,
                                               ushort* __restrict__ xb, int n4) {
  int i = blockIdx.x * 256 + threadIdx.x;
  if (i >= n4) return;
  float4 v = ((const float4*)x)[i];
  ushort4 o; o.x = f2b(v.x); o.y = f2b(v.y); o.z = f2b(v.z); o.w = f2b(v.w);
  ((ushort4*)xb)[i] = o;
}

__global__ __launch_bounds__(256) void k_cvt_w(const float* __restrict__ W0,
                                               const float* __restrict__ W1,
                                               const float* __restrict__ W2,
                                               ushort* __restrict__ Wb) {
  const float* src = (blockIdx.x == 0) ? W0 : (blockIdx.x == 1) ? W1 : W2;
  ushort* dst = Wb + blockIdx.x * 16384;
  for (int i = threadIdx.x * 4; i < 16384; i += 1024) {
    float4 v = *(const float4*)(src + i);
    ushort4 o; o.x = f2b(v.x); o.y = f2b(v.y); o.z = f2b(v.z); o.w = f2b(v.w);
    *(ushort4*)(dst + i) = o;
  }
}

// ---------------- degree count ----------------
__global__ __launch_bounds__(256) void k_count(const int* __restrict__ col,
                                               int* __restrict__ cnt, int E) {
  int e = blockIdx.x * 256 + threadIdx.x;
  if (e < E) atomicAdd(&cnt[col[e]], 1);
}

// ---------------- scan phase A ----------------
__global__ __launch_bounds__(256) void k_blockscan(const int* __restrict__ cnt,
                                                   int* __restrict__ off,
                                                   float* __restrict__ dinv,
                                                   int* __restrict__ btot, int N) {
  __shared__ int ws[4];
  int t = threadIdx.x, lane = t & 63, wv = t >> 6;
  int i = blockIdx.x * 256 + t;
  int v = (i < N) ? cnt[i] : 0;
  int inc = v;
#pragma unroll
  for (int o = 1; o < 64; o <<= 1) {
    int u = __shfl_up(inc, o);
    if (lane >= o) inc += u;
  }
  if (lane == 63) ws[wv] = inc;
  __syncthreads();
  if (t == 0) {
    int s = 0;
#pragma unroll
    for (int w = 0; w < 4; ++w) { int tmp = ws[w]; ws[w] = s; s += tmp; }
  }
  __syncthreads();
  int excl = ws[wv] + inc - v;
  if (i < N) {
    off[i] = excl;
    dinv[i] = rsqrtf((float)v + 1.0f);
  }
  if (t == 255) btot[blockIdx.x] = excl + v;
}

// ---------------- scan phase B ----------------
__global__ __launch_bounds__(256) void k_scanb(const int* __restrict__ btot,
                                               int* __restrict__ bpre,
                                               int* __restrict__ off, int N, int NB) {
  __shared__ int ws[4];
  int t = threadIdx.x, lane = t & 63, wv = t >> 6;
  int v = (t < NB) ? btot[t] : 0;
  int inc = v;
#pragma unroll
  for (int o = 1; o < 64; o <<= 1) {
    int u = __shfl_up(inc, o);
    if (lane >= o) inc += u;
  }
  if (lane == 63) ws[wv] = inc;
  __syncthreads();
  if (t == 0) {
    int s = 0;
#pragma unroll
    for (int w = 0; w < 4; ++w) { int tmp = ws[w]; ws[w] = s; s += tmp; }
  }
  __syncthreads();
  int excl = ws[wv] + inc - v;
  if (t < NB) bpre[t] = excl;
  if (t == 255) off[N] = excl + v;
}

// ---------------- scan phase C ----------------
__global__ __launch_bounds__(256) void k_addoff(int* __restrict__ off,
                                                const int* __restrict__ bpre,
                                                int* __restrict__ cursor, int N) {
  int i = blockIdx.x * 256 + threadIdx.x;
  if (i < N) {
    int o = off[i] + bpre[blockIdx.x];
    off[i] = o;
    cursor[i] = o;
  }
}

// ---------------- scatter edges into CSR ----------------
__global__ __launch_bounds__(256) void k_scatter(const int* __restrict__ ei,
                                                 const float* __restrict__ dinv,
                                                 int* __restrict__ cursor,
                                                 int2* __restrict__ edata, int E) {
  int e = blockIdx.x * 256 + threadIdx.x;
  if (e >= E) return;
  int s = ei[e], d = ei[E + e];
  float w = dinv[s] * dinv[d];
  int p = atomicAdd(&cursor[d], 1);
  int2 v; v.x = s; v.y = __float_as_int(w);
  edata[p] = v;
}

// ---------------- MFMA GEMM: h_all[r][m*128+c] = bf16(x @ W_m^T + b_m) ----
// W resident in registers per wave (8 col-tiles x 4 K-chunks).
// A-frag: lane holds x[r0+(l&15)][32*kc + 8*(l>>4) + j]  (8 contiguous bf16)
// B-frag: lane holds W[ct*16+(l&15)][32*kc + 8*(l>>4) + j]
// C/D:    reg j -> row r0 + 4*(l>>4)+j, col ct*16 + (l&15)   [guide §3, m89]
__global__ __launch_bounds__(256, 2) void k_gemm_mfma(
    const ushort* __restrict__ xb, const ushort* __restrict__ Wb,
    const float* __restrict__ b_hp, const float* __restrict__ b_lp,
    const float* __restrict__ b_i,
    ushort* __restrict__ h_all, int N) {
  int m = blockIdx.y;
  const float* bias = (m == 0) ? b_hp : (m == 1) ? b_lp : b_i;
  int lane = (int)threadIdx.x & 63, wv = (int)threadIdx.x >> 6;
  int r = lane & 15, g = lane >> 4;

  const ushort* wp = Wb + m * 16384 + r * 128 + g * 8;
  bf16x8 Bf[8][4];
#pragma unroll
  for (int ct = 0; ct < 8; ++ct)
#pragma unroll
    for (int kc = 0; kc < 4; ++kc)
      Bf[ct][kc] = *(const bf16x8*)(const void*)(wp + ct * 2048 + kc * 32);

  float bv[8];
#pragma unroll
  for (int ct = 0; ct < 8; ++ct) bv[ct] = bias[ct * 16 + r];

  int NT = N >> 4;
  int stride = gridDim.x * 4;
  int t = blockIdx.x * 4 + wv;
  if (t >= NT) return;

  const ushort* ap0 = xb + r * 128 + g * 8;
  bf16x8 Af[4];
#pragma unroll
  for (int kc = 0; kc < 4; ++kc)
    Af[kc] = *(const bf16x8*)(const void*)(ap0 + (size_t)t * 2048 + kc * 32);

  while (t < NT) {
    int tn = t + stride;
    bf16x8 Afn[4];
    if (tn < NT) {
#pragma unroll
      for (int kc = 0; kc < 4; ++kc)
        Afn[kc] = *(const bf16x8*)(const void*)(ap0 + (size_t)tn * 2048 + kc * 32);
    }
    f32x4 acc[8];
#pragma unroll
    for (int ct = 0; ct < 8; ++ct) {
      f32x4 c; c[0] = bv[ct]; c[1] = bv[ct]; c[2] = bv[ct]; c[3] = bv[ct];
      acc[ct] = c;
    }
#pragma unroll
    for (int kc = 0; kc < 4; ++kc)
#pragma unroll
      for (int ct = 0; ct < 8; ++ct)
        acc[ct] = __builtin_amdgcn_mfma_f32_16x16x32_bf16(Af[kc], Bf[ct][kc], acc[ct], 0, 0, 0);

    ushort* op = h_all + (size_t)((t << 4) + g * 4) * 384 + m * 128 + r;
#pragma unroll
    for (int ct = 0; ct < 8; ++ct)
#pragma unroll
      for (int j = 0; j < 4; ++j) {
        float v = acc[ct][j];
        if (m == 2) v = fmaxf(v, 0.f);
        op[(size_t)j * 384 + ct * 16] = f2b(v);
      }
#pragma unroll
    for (int kc = 0; kc < 4; ++kc) Af[kc] = Afn[kc];
    t = tn;
  }
}

// ---------------- fused aggregation + epilogue (one wave per node) ----------------
// h_all row: [0:128]=h_hp, [128:256]=h_lp, [256:384]=H_i (bf16).
__global__ __launch_bounds__(256) void k_agg_final(
    const ushort* __restrict__ h_all, const float* __restrict__ dinv,
    const int* __restrict__ off, const int2* __restrict__ edata,
    const float* __restrict__ wlh, const float* __restrict__ wll,
    const float* __restrict__ wli,
    const float* __restrict__ pbh, const float* __restrict__ pbl,
    const float* __restrict__ pbi,
    float* __restrict__ out, int N) {
  int wv = __builtin_amdgcn_readfirstlane((int)threadIdx.x >> 6);
  int lane = (int)threadIdx.x & 63;
  int node = blockIdx.x * 4 + wv;
  if (node >= N) return;

  const ushort* hb = h_all + 4 * lane;  // + s*384 per edge; lanes cover 256 hp|lp vals
  int p0 = off[node], p1 = off[node + 1];

  float4 a0 = {0,0,0,0}, a1 = {0,0,0,0}, a2 = {0,0,0,0}, a3 = {0,0,0,0};
  int p = p0;
  for (; p + 4 <= p1; p += 4) {
    int2 e0 = edata[p], e1 = edata[p+1], e2 = edata[p+2], e3 = edata[p+3];
    uint2 u0 = *(const uint2*)(const void*)(hb + (size_t)e0.x * 384);
    uint2 u1 = *(const uint2*)(const void*)(hb + (size_t)e1.x * 384);
    uint2 u2 = *(const uint2*)(const void*)(hb + (size_t)e2.x * 384);
    uint2 u3 = *(const uint2*)(const void*)(hb + (size_t)e3.x * 384);
    fma4(a0, __int_as_float(e0.y), u0);
    fma4(a1, __int_as_float(e1.y), u1);
    fma4(a2, __int_as_float(e2.y), u2);
    fma4(a3, __int_as_float(e3.y), u3);
  }
  for (; p < p1; ++p) {
    int2 e = edata[p];
    uint2 u = *(const uint2*)(const void*)(hb + (size_t)e.x * 384);
    fma4(a0, __int_as_float(e.y), u);
  }
  float4 own;
  own.x = (a0.x + a1.x) + (a2.x + a3.x);
  own.y = (a0.y + a1.y) + (a2.y + a3.y);
  own.z = (a0.z + a1.z) + (a2.z + a3.z);
  own.w = (a0.w + a1.w) + (a2.w + a3.w);

  float di = dinv[node], wself = di * di;
  float4 sv = unpack4(*(const uint2*)(const void*)(hb + (size_t)node * 384));
  own.x = fmaf(wself, sv.x, own.x); own.y = fmaf(wself, sv.y, own.y);
  own.z = fmaf(wself, sv.z, own.z); own.w = fmaf(wself, sv.w, own.w);

  float4 oth = shfl_xor4(own, 32);
  float4 svo = shfl_xor4(sv, 32);
  bool hpside = (lane < 32);
  float4 hpSelf, aggHp, aggLp;
  hpSelf.x = hpside ? sv.x : svo.x; hpSelf.y = hpside ? sv.y : svo.y;
  hpSelf.z = hpside ? sv.z : svo.z; hpSelf.w = hpside ? sv.w : svo.w;
  aggHp.x = hpside ? own.x : oth.x; aggHp.y = hpside ? own.y : oth.y;
  aggHp.z = hpside ? own.z : oth.z; aggHp.w = hpside ? own.w : oth.w;
  aggLp.x = hpside ? oth.x : own.x; aggLp.y = hpside ? oth.y : own.y;
  aggLp.z = hpside ? oth.z : own.z; aggLp.w = hpside ? oth.w : own.w;

  float4 Hh, Hl;
  Hh.x = fmaxf(hpSelf.x - aggHp.x, 0.f); Hh.y = fmaxf(hpSelf.y - aggHp.y, 0.f);
  Hh.z = fmaxf(hpSelf.z - aggHp.z, 0.f); Hh.w = fmaxf(hpSelf.w - aggHp.w, 0.f);
  Hl.x = fmaxf(aggLp.x, 0.f); Hl.y = fmaxf(aggLp.y, 0.f);
  Hl.z = fmaxf(aggLp.z, 0.f); Hl.w = fmaxf(aggLp.w, 0.f);

  int c4 = 4 * (lane & 31);
  float4 hi4 = unpack4(*(const uint2*)(const void*)(h_all + (size_t)node * 384 + 256 + c4));
  float4 wh = *(const float4*)(wlh + c4);
  float4 wl = *(const float4*)(wll + c4);
  float4 wi = *(const float4*)(wli + c4);

  float dh = Hh.x * wh.x + Hh.y * wh.y + Hh.z * wh.z + Hh.w * wh.w;
  float dl = Hl.x * wl.x + Hl.y * wl.y + Hl.z * wl.z + Hl.w * wl.w;
  float dd = hi4.x * wi.x + hi4.y * wi.y + hi4.z * wi.z + hi4.w * wi.w;
#pragma unroll
  for (int o = 32; o > 0; o >>= 1) {
    dh += __shfl_xor(dh, o);
    dl += __shfl_xor(dl, o);
    dd += __shfl_xor(dd, o);
  }
  float a_h = 1.f / (1.f + __expf(-(0.5f * dh + pbh[0])));
  float a_l = 1.f / (1.f + __expf(-(0.5f * dl + pbl[0])));
  float a_i = 1.f / (1.f + __expf(-(0.5f * dd + pbi[0])));

  if (hpside) {
    float4 o4;
    o4.x = a_h * Hh.x + a_l * Hl.x + a_i * hi4.x;
    o4.y = a_h * Hh.y + a_l * Hl.y + a_i * hi4.y;
    o4.z = a_h * Hh.z + a_l * Hl.z + a_i * hi4.z;
    o4.w = a_h * Hh.w + a_l * Hl.w + a_i * hi4.w;
    *(float4*)(out + (size_t)node * 128 + c4) = o4;
  }
}

// ---------------- launch ----------------
extern "C" void kernel_launch(void* const* d_in, const int* in_sizes, int n_in,
                              void* d_out, int out_size, void* d_ws, size_t ws_size,
                              hipStream_t stream) {
  const float* x     = (const float*)d_in[0];
  const int*   ei    = (const int*)d_in[1];
  const float* W_hp  = (const float*)d_in[2];
  const float* b_hp  = (const float*)d_in[3];
  const float* W_lp  = (const float*)d_in[4];
  const float* b_lp  = (const float*)d_in[5];
  const float* W_i   = (const float*)d_in[6];
  const float* b_i   = (const float*)d_in[7];
  const float* wlh   = (const float*)d_in[8];
  const float* pbh   = (const float*)d_in[9];
  const float* wll   = (const float*)d_in[10];
  const float* pbl   = (const float*)d_in[11];
  const float* wli   = (const float*)d_in[12];
  const float* pbi   = (const float*)d_in[13];
  float* out = (float*)d_out;

  int N = in_sizes[0] / 128;
  int E = in_sizes[1] / 2;
  int NB = (N + 255) / 256;

  ushort* xb    = (ushort*)d_ws;                  // N*128
  ushort* h_all = xb + (size_t)N * 128;           // N*384
  ushort* Wb    = h_all + (size_t)N * 384;        // 3*16384
  int2*   edata = (int2*)(Wb + 3 * 16384);        // E
  float*  dinv  = (float*)(edata + E);            // N
  int*    cnt   = (int*)(dinv + N);               // N
  int*    off   = cnt + N;                        // N+1
  int*    cursor= off + N + 1;                    // N
  int*    btot  = cursor + N;                     // NB
  int*    bpre  = btot + NB;                      // NB

  hipMemsetAsync(cnt, 0, sizeof(int) * N, stream);
  k_cvt_x<<<(N * 128 / 4 + 255) / 256, 256, 0, stream>>>(x, xb, N * 128 / 4);
  k_cvt_w<<<3, 256, 0, stream>>>(W_hp, W_lp, W_i, Wb);
  k_count<<<(E + 255) / 256, 256, 0, stream>>>(ei + E, cnt, E);
  k_blockscan<<<NB, 256, 0, stream>>>(cnt, off, dinv, btot, N);
  k_scanb<<<1, 256, 0, stream>>>(btot, bpre, off, N, NB);
  k_addoff<<<NB, 256, 0, stream>>>(off, bpre, cursor, N);
  k_scatter<<<(E + 255) / 256, 256, 0, stream>>>(ei, dinv, cursor, edata, E);
  k_gemm_mfma<<<dim3(200, 3), 256, 0, stream>>>(xb, Wb, b_hp, b_lp, b_i, h_all, N);
  k_agg_final<<<(N + 3) / 4, 256, 0, stream>>>(
      h_all, dinv, off, edata, wlh, wll, wli, pbh, pbl, pbi, out, N);
}